// Round 1
// baseline (319.218 us; speedup 1.0000x reference)
//
#include <hip/hip_runtime.h>

typedef unsigned short u16;
typedef __bf16 bf16x8 __attribute__((ext_vector_type(8)));
typedef float f32x4 __attribute__((ext_vector_type(4)));

#define MFMA16(a,b,c) __builtin_amdgcn_mfma_f32_16x16x32_bf16(a,b,c,0,0,0)

static __device__ __forceinline__ u16 f2bf(float f){
  unsigned u = __builtin_bit_cast(unsigned, f);
  u += 0x7fffu + ((u>>16)&1u);
  return (u16)(u>>16);
}
static __device__ __forceinline__ int swz256(int r,int c){ return r*256 + (c ^ ((r&7)<<4)); }
static __device__ __forceinline__ int swz128(int r,int c){ return r*128 + (c ^ ((r&7)<<4)); }

// ---------------- fp32 -> bf16 convert ----------------
__global__ void conv_f2b(const float* __restrict__ in, u16* __restrict__ out, int n4){
  int i = blockIdx.x*256 + threadIdx.x;
  if (i >= n4) return;
  float4 f = reinterpret_cast<const float4*>(in)[i];
  ushort4 o; o.x=f2bf(f.x); o.y=f2bf(f.y); o.z=f2bf(f.z); o.w=f2bf(f.w);
  reinterpret_cast<ushort4*>(out)[i] = o;
}

// ---------------- bf16 NT GEMM: C[m][n] = sum_k A[m][k]*B[n][k] + bias[n] ----------------
// MODE 0: bf16 out, natural [M][N].  MODE 1: bf16 out transposed per-b: Cb[(b*1024+n)*1024 + (m%1024)].
// MODE 2: fp32 out natural, + bias + resid.
template<int MODE>
__global__ __launch_bounds__(256) void gemm_nt(const u16* __restrict__ A, const u16* __restrict__ Bw,
    const float* __restrict__ bias, const float* __restrict__ resid,
    u16* __restrict__ Cb, float* __restrict__ Cf, int M, int N, int K)
{
  __shared__ uint4 ldsv[2048];               // 32 KB: A tile 128x64, B tile 128x64 (bf16, swizzled)
  char* la = (char*)ldsv;
  char* lb = la + 16384;
  const int tid = threadIdx.x, lane = tid&63, w = tid>>6;
  const int l15 = lane&15, l4 = lane>>4;
  const int wm = w&1, wn = w>>1;
  const int mb = blockIdx.x, nb = blockIdx.y;
  const f32x4 zero4 = {0.f,0.f,0.f,0.f};
  f32x4 acc[4][4];
  #pragma unroll
  for (int i=0;i<4;++i)
    #pragma unroll
    for (int j=0;j<4;++j) acc[i][j] = zero4;

  for (int k0=0;k0<K;k0+=64){
    __syncthreads();
    #pragma unroll
    for (int it=0; it<4; ++it){
      int idx = tid + it*256;
      int row = idx>>3, c = idx&7;
      uint4 va = *reinterpret_cast<const uint4*>(A + (size_t)(mb*128+row)*K + k0 + c*8);
      *reinterpret_cast<uint4*>(la + swz128(row, c*16)) = va;
      uint4 vb = *reinterpret_cast<const uint4*>(Bw + (size_t)(nb*128+row)*K + k0 + c*8);
      *reinterpret_cast<uint4*>(lb + swz128(row, c*16)) = vb;
    }
    __syncthreads();
    #pragma unroll
    for (int kk=0;kk<2;++kk){
      bf16x8 af[4], bfr[4];
      #pragma unroll
      for (int i=0;i<4;++i){
        af[i]  = *reinterpret_cast<const bf16x8*>(la + swz128(wm*64+i*16+l15, (kk*32+l4*8)*2));
        bfr[i] = *reinterpret_cast<const bf16x8*>(lb + swz128(wn*64+i*16+l15, (kk*32+l4*8)*2));
      }
      #pragma unroll
      for (int i=0;i<4;++i)
        #pragma unroll
        for (int j=0;j<4;++j)
          acc[i][j] = MFMA16(af[i], bfr[j], acc[i][j]);
    }
  }
  #pragma unroll
  for (int j=0;j<4;++j){
    int col = nb*128 + wn*64 + j*16 + l15;
    float bv = bias[col];
    #pragma unroll
    for (int i=0;i<4;++i){
      int row0 = mb*128 + wm*64 + i*16 + l4*4;
      if (MODE == 0){
        #pragma unroll
        for (int r=0;r<4;++r)
          Cb[(size_t)(row0+r)*N + col] = f2bf(acc[i][j][r] + bv);
      } else if (MODE == 1){
        int bb = row0 >> 10, kp = row0 & 1023;
        ushort4 o;
        o.x = f2bf(acc[i][j][0]+bv); o.y = f2bf(acc[i][j][1]+bv);
        o.z = f2bf(acc[i][j][2]+bv); o.w = f2bf(acc[i][j][3]+bv);
        *reinterpret_cast<ushort4*>(Cb + (size_t)(bb*1024+col)*1024 + kp) = o;
      } else {
        #pragma unroll
        for (int r=0;r<4;++r){
          size_t off = (size_t)(row0+r)*N + col;
          Cf[off] = acc[i][j][r] + bv + resid[off];
        }
      }
    }
  }
}

// ---------------- fused attention ----------------
// grid (16, B=8, H=8), block 256 (4 waves, 16 q-rows each). KVB=64.
// qh,kh: [b][l][h*128+d] bf16.  vt: [b][h*128+d][l] bf16 (pre-transposed).
__global__ __launch_bounds__(256) void attn_fused(const u16* __restrict__ qh,
    const u16* __restrict__ kh, const u16* __restrict__ vt,
    const float* __restrict__ oldsc, const float* __restrict__ fmask,
    float* __restrict__ raw, u16* __restrict__ ao)
{
  __shared__ uint4 ldsv[2560];    // 40 KB
  char* lk_ = (char*)ldsv;        // K tile: 64 rows x 128 bf16 (256B rows, swz256)
  char* lv_ = lk_ + 16384;        // V^T tile: 128 rows(d) x 64 bf16 (128B rows, swz128)
  char* lp_ = lk_ + 32768;        // P: 64 rows(q) x 64 bf16 (128B rows, swz128)
  const int tid = threadIdx.x, lane = tid&63, w = tid>>6;
  const int l15 = lane&15, l4 = lane>>4;
  const int qb = blockIdx.x, b = blockIdx.y, h = blockIdx.z;
  const float invT = 0.088388347648318447f;   // 1/sqrt(128)
  const f32x4 zero4 = {0.f,0.f,0.f,0.f};

  bf16x8 qf[4];    // Q fragment: row = this wave's q (l15), k = d (contiguous 8)
  {
    const u16* qp = qh + (size_t)(b*1024 + qb*64 + w*16 + l15)*1024 + h*128 + l4*8;
    #pragma unroll
    for (int kk=0;kk<4;++kk)
      qf[kk] = __builtin_bit_cast(bf16x8, *reinterpret_cast<const uint4*>(qp + kk*32));
  }
  f32x4 oacc[8];
  #pragma unroll
  for (int i=0;i<8;++i) oacc[i] = zero4;
  float mr[4], lr[4];
  #pragma unroll
  for (int r=0;r<4;++r){ mr[r] = -3.0e38f; lr[r] = 0.f; }

  for (int kt=0; kt<16; ++kt){
    __syncthreads();
    #pragma unroll
    for (int it=0; it<4; ++it){
      int idx = tid + it*256;
      { int row = idx>>4, c = idx&15;   // K: 64 rows x 16 chunks
        uint4 t = *reinterpret_cast<const uint4*>(kh + (size_t)(b*1024 + kt*64 + row)*1024 + h*128 + c*8);
        *reinterpret_cast<uint4*>(lk_ + swz256(row, c*16)) = t; }
      { int row = idx>>3, c = idx&7;    // V^T: 128 rows x 8 chunks
        uint4 t = *reinterpret_cast<const uint4*>(vt + (size_t)(b*1024 + h*128 + row)*1024 + kt*64 + c*8);
        *reinterpret_cast<uint4*>(lv_ + swz128(row, c*16)) = t; }
    }
    __syncthreads();
    // S = Q K^T  (C layout: col kv = l15 (+16*fj), row q = l4*4+r)
    f32x4 fs[4];
    #pragma unroll
    for (int fj=0;fj<4;++fj){
      f32x4 s = zero4;
      #pragma unroll
      for (int kk=0;kk<4;++kk){
        bf16x8 kf = *reinterpret_cast<const bf16x8*>(lk_ + swz256(fj*16+l15, (kk*32+l4*8)*2));
        s = MFMA16(qf[kk], kf, s);
      }
      fs[fj] = s;
    }
    const int qglob = qb*64 + w*16 + l4*4;
    size_t rbase  = ((size_t)(h*8 + b)*1024 + qglob)*1024 + kt*64;
    size_t mbase2 = ((size_t)b*1024 + qglob)*1024 + kt*64;
    float tm[4];
    #pragma unroll
    for (int r=0;r<4;++r){
      float mx = -3.0e38f;
      #pragma unroll
      for (int fj=0;fj<4;++fj){
        int kvc = fj*16 + l15;
        float old = oldsc[rbase + (size_t)r*1024 + kvc];
        float rv = fs[fj][r] + old;
        raw[rbase + (size_t)r*1024 + kvc] = rv;
        float mk = fmask[mbase2 + (size_t)r*1024 + kvc];
        float sc = (rv - 1.0e8f*(1.0f - mk)) * invT;
        fs[fj][r] = sc;
        mx = fmaxf(mx, sc);
      }
      tm[r] = mx;
    }
    #pragma unroll
    for (int o=1;o<16;o<<=1){
      #pragma unroll
      for (int r=0;r<4;++r) tm[r] = fmaxf(tm[r], __shfl_xor(tm[r], o));
    }
    #pragma unroll
    for (int r=0;r<4;++r){
      float mn  = fmaxf(mr[r], tm[r]);
      float esc = __expf(mr[r] - mn);
      mr[r] = mn;
      lr[r] *= esc;
      #pragma unroll
      for (int nf=0;nf<8;++nf) oacc[nf][r] *= esc;
      int prow = w*16 + l4*4 + r;
      #pragma unroll
      for (int fj=0;fj<4;++fj){
        float p = __expf(fs[fj][r] - mn);
        lr[r] += p;                 // per-lane partial row-sum; reduced at the end
        *reinterpret_cast<u16*>(lp_ + swz128(prow, (fj*16+l15)*2)) = f2bf(p);
      }
    }
    // PV: A = P (row q=l15, kv contiguous), B = V^T rows (col d=l15, kv contiguous)
    #pragma unroll
    for (int kkv=0;kkv<2;++kkv){
      bf16x8 pf = *reinterpret_cast<const bf16x8*>(lp_ + swz128(w*16+l15, (kkv*32+l4*8)*2));
      #pragma unroll
      for (int nf=0;nf<8;++nf){
        bf16x8 vf = *reinterpret_cast<const bf16x8*>(lv_ + swz128(nf*16+l15, (kkv*32+l4*8)*2));
        oacc[nf] = MFMA16(pf, vf, oacc[nf]);
      }
    }
  }
  #pragma unroll
  for (int o=1;o<16;o<<=1){
    #pragma unroll
    for (int r=0;r<4;++r) lr[r] += __shfl_xor(lr[r], o);
  }
  #pragma unroll
  for (int nf=0;nf<8;++nf){
    int col = h*128 + nf*16 + l15;
    #pragma unroll
    for (int r=0;r<4;++r){
      size_t orow = (size_t)(b*1024 + qb*64 + w*16 + l4*4 + r);
      ao[orow*1024 + col] = f2bf(oacc[nf][r] * (1.0f/lr[r]));
    }
  }
}

// ---------------- LayerNorm (in-place, row=1024) ----------------
__global__ __launch_bounds__(256) void ln_k(float* __restrict__ io,
    const float* __restrict__ g, const float* __restrict__ bb)
{
  const int lane = threadIdx.x & 63, w = threadIdx.x >> 6;
  size_t row = (size_t)blockIdx.x*4 + w;
  float4* p = reinterpret_cast<float4*>(io + row*1024);
  float4 x[4];
  float s = 0.f, s2 = 0.f;
  #pragma unroll
  for (int i=0;i<4;++i){
    x[i] = p[lane + i*64];
    s  += x[i].x + x[i].y + x[i].z + x[i].w;
    s2 += x[i].x*x[i].x + x[i].y*x[i].y + x[i].z*x[i].z + x[i].w*x[i].w;
  }
  #pragma unroll
  for (int o=1;o<64;o<<=1){ s += __shfl_xor(s,o); s2 += __shfl_xor(s2,o); }
  float mean = s * 0.0009765625f;
  float var  = s2 * 0.0009765625f - mean*mean;
  float rstd = rsqrtf(var + 1e-5f);
  const float4* gp = reinterpret_cast<const float4*>(g);
  const float4* bp = reinterpret_cast<const float4*>(bb);
  #pragma unroll
  for (int i=0;i<4;++i){
    float4 gg = gp[lane+i*64], bv = bp[lane+i*64], y;
    y.x = (x[i].x-mean)*rstd*gg.x + bv.x;
    y.y = (x[i].y-mean)*rstd*gg.y + bv.y;
    y.z = (x[i].z-mean)*rstd*gg.z + bv.z;
    y.w = (x[i].w-mean)*rstd*gg.w + bv.w;
    p[lane+i*64] = y;
  }
}

extern "C" void kernel_launch(void* const* d_in, const int* in_sizes, int n_in,
                              void* d_out, int out_size, void* d_ws, size_t ws_size,
                              hipStream_t stream)
{
  const float* q    = (const float*)d_in[0];
  const float* k    = (const float*)d_in[1];
  const float* v    = (const float*)d_in[2];
  const float* olds = (const float*)d_in[3];
  const float* fm   = (const float*)d_in[4];
  const float* wq   = (const float*)d_in[5];
  const float* bq   = (const float*)d_in[6];
  const float* wk   = (const float*)d_in[7];
  const float* bk   = (const float*)d_in[8];
  const float* wv   = (const float*)d_in[9];
  const float* bv   = (const float*)d_in[10];
  const float* wfc  = (const float*)d_in[11];
  const float* bfc  = (const float*)d_in[12];
  const float* lng  = (const float*)d_in[13];
  const float* lnb  = (const float*)d_in[14];
  float* out = (float*)d_out;
  float* raw = out + 8388608;          // 8*1024*1024 fp32 "out", then 64M fp32 "raw"

  u16* ws  = (u16*)d_ws;
  u16* qbf = ws;                        // 8192x512
  u16* kbf = qbf + 4194304;             // 8192x512
  u16* vbf = kbf + 4194304;             // 8192x1024
  u16* wqb = vbf + 8388608;             // 1024x512
  u16* wkb = wqb + 524288;
  u16* wvb = wkb + 524288;              // 1024x1024
  u16* wfb = wvb + 1048576;
  u16* qhb = wfb + 1048576;             // 8192x1024
  u16* khb = qhb + 8388608;
  u16* vtb = khb + 8388608;             // [b][h*128+d][1024]
  u16* aob = vtb + 8388608;             // 8192x1024

  conv_f2b<<<4096,256,0,stream>>>(q,   qbf, 1048576);
  conv_f2b<<<4096,256,0,stream>>>(k,   kbf, 1048576);
  conv_f2b<<<8192,256,0,stream>>>(v,   vbf, 2097152);
  conv_f2b<<<512, 256,0,stream>>>(wq,  wqb, 131072);
  conv_f2b<<<512, 256,0,stream>>>(wk,  wkb, 131072);
  conv_f2b<<<1024,256,0,stream>>>(wv,  wvb, 262144);
  conv_f2b<<<1024,256,0,stream>>>(wfc, wfb, 262144);

  gemm_nt<0><<<dim3(64,8),256,0,stream>>>(qbf, wqb, bq, nullptr, qhb, nullptr, 8192,1024,512);
  gemm_nt<0><<<dim3(64,8),256,0,stream>>>(kbf, wkb, bk, nullptr, khb, nullptr, 8192,1024,512);
  gemm_nt<1><<<dim3(64,8),256,0,stream>>>(vbf, wvb, bv, nullptr, vtb, nullptr, 8192,1024,1024);

  attn_fused<<<dim3(16,8,8),256,0,stream>>>(qhb, khb, vtb, olds, fm, raw, aob);

  gemm_nt<2><<<dim3(64,8),256,0,stream>>>(aob, wfb, bfc, v, nullptr, out, 8192,1024,1024);
  ln_k<<<2048,256,0,stream>>>(out, lng, lnb);
}

// Round 2
// 316.144 us; speedup vs baseline: 1.0097x; 1.0097x over previous
//
#include <hip/hip_runtime.h>

typedef unsigned short u16;
typedef __bf16 bf16x8 __attribute__((ext_vector_type(8)));
typedef float f32x4 __attribute__((ext_vector_type(4)));

#define MFMA16(a,b,c) __builtin_amdgcn_mfma_f32_16x16x32_bf16(a,b,c,0,0,0)

static __device__ __forceinline__ u16 f2bf(float f){
  unsigned u = __builtin_bit_cast(unsigned, f);
  u += 0x7fffu + ((u>>16)&1u);
  return (u16)(u>>16);
}
static __device__ __forceinline__ int swz256(int r,int c){ return r*256 + (c ^ ((r&7)<<4)); }
static __device__ __forceinline__ int swz128(int r,int c){ return r*128 + (c ^ ((r&7)<<4)); }

// async global->LDS, 16B per lane; lds dest = wave-uniform base + lane*16
static __device__ __forceinline__ void gload16(const void* g, void* l){
  __builtin_amdgcn_global_load_lds(
      (const __attribute__((address_space(1))) unsigned int*)g,
      (__attribute__((address_space(3))) unsigned int*)l, 16, 0, 0);
}

// ---------------- fp32 -> bf16 convert ----------------
__global__ void conv_f2b(const float* __restrict__ in, u16* __restrict__ out, int n4){
  int i = blockIdx.x*256 + threadIdx.x;
  if (i >= n4) return;
  float4 f = reinterpret_cast<const float4*>(in)[i];
  ushort4 o; o.x=f2bf(f.x); o.y=f2bf(f.y); o.z=f2bf(f.z); o.w=f2bf(f.w);
  reinterpret_cast<ushort4*>(out)[i] = o;
}

// ---------------- bf16 NT GEMM: C[m][n] = sum_k A[m][k]*B[n][k] + bias[n] ----------------
// MODE 0: bf16 out [M][N].  MODE 1: bf16 out transposed per-b: Cb[(b*1024+n)*1024 + (m%1024)].
// MODE 2: fp32 out natural, + bias + resid.
template<int MODE>
__global__ __launch_bounds__(256) void gemm_nt(const u16* __restrict__ A, const u16* __restrict__ Bw,
    const float* __restrict__ bias, const float* __restrict__ resid,
    u16* __restrict__ Cb, float* __restrict__ Cf, int M, int N, int K)
{
  __shared__ uint4 ldsv[2048];               // 32 KB: A tile 128x64, B tile 128x64 (bf16, swizzled)
  char* la = (char*)ldsv;
  char* lb = la + 16384;
  const int tid = threadIdx.x, lane = tid&63, w = tid>>6;
  const int l15 = lane&15, l4 = lane>>4;
  const int wm = w&1, wn = w>>1;
  const int mb = blockIdx.x, nb = blockIdx.y;
  const f32x4 zero4 = {0.f,0.f,0.f,0.f};
  f32x4 acc[4][4];
  #pragma unroll
  for (int i=0;i<4;++i)
    #pragma unroll
    for (int j=0;j<4;++j) acc[i][j] = zero4;

  for (int k0=0;k0<K;k0+=64){
    __syncthreads();
    // stage via global_load_lds w16; LDS linear dest, source pre-swizzled so that
    // physical chunk c_phys = c_log ^ (row&7)  (matches swz128 on the read side)
    #pragma unroll
    for (int it=0; it<4; ++it){
      int slot = it*256 + tid;
      int r = slot>>3, cg = (slot&7) ^ (r&7);
      gload16(A + (size_t)(mb*128+r)*K + k0 + cg*8, la + (it*256 + w*64)*16);
      gload16(Bw + (size_t)(nb*128+r)*K + k0 + cg*8, lb + (it*256 + w*64)*16);
    }
    __syncthreads();
    #pragma unroll
    for (int kk=0;kk<2;++kk){
      bf16x8 af[4], bfr[4];
      #pragma unroll
      for (int i=0;i<4;++i){
        af[i]  = *reinterpret_cast<const bf16x8*>(la + swz128(wm*64+i*16+l15, (kk*32+l4*8)*2));
        bfr[i] = *reinterpret_cast<const bf16x8*>(lb + swz128(wn*64+i*16+l15, (kk*32+l4*8)*2));
      }
      #pragma unroll
      for (int i=0;i<4;++i)
        #pragma unroll
        for (int j=0;j<4;++j)
          acc[i][j] = MFMA16(af[i], bfr[j], acc[i][j]);
    }
  }
  #pragma unroll
  for (int j=0;j<4;++j){
    int col = nb*128 + wn*64 + j*16 + l15;
    float bv = bias[col];
    #pragma unroll
    for (int i=0;i<4;++i){
      int row0 = mb*128 + wm*64 + i*16 + l4*4;
      if (MODE == 0){
        #pragma unroll
        for (int r=0;r<4;++r)
          Cb[(size_t)(row0+r)*N + col] = f2bf(acc[i][j][r] + bv);
      } else if (MODE == 1){
        int bb = row0 >> 10, kp = row0 & 1023;
        ushort4 o;
        o.x = f2bf(acc[i][j][0]+bv); o.y = f2bf(acc[i][j][1]+bv);
        o.z = f2bf(acc[i][j][2]+bv); o.w = f2bf(acc[i][j][3]+bv);
        *reinterpret_cast<ushort4*>(Cb + (size_t)(bb*1024+col)*1024 + kp) = o;
      } else {
        #pragma unroll
        for (int r=0;r<4;++r){
          size_t off = (size_t)(row0+r)*N + col;
          Cf[off] = acc[i][j][r] + bv + resid[off];
        }
      }
    }
  }
}

// ---------------- fused attention ----------------
// grid (16, B=8, H=8), block 256 (4 waves, 16 q-rows each). KVB=64.
// qh,kh: [b][l][h*128+d] bf16.  vt: [b][h*128+d][l] bf16 (pre-transposed).
// K is staged PERMUTED: LDS slot-row s holds kv row (s&15)*4+(s>>4), so the
// S-tile C-layout col for (fragment fj, lane l15) is kv = l15*4+fj ->
// each lane owns 4 CONSECUTIVE kv columns -> float4 old/mask/raw access.
__global__ __launch_bounds__(256) void attn_fused(const u16* __restrict__ qh,
    const u16* __restrict__ kh, const u16* __restrict__ vt,
    const float* __restrict__ oldsc, const float* __restrict__ fmask,
    float* __restrict__ raw, u16* __restrict__ ao)
{
  __shared__ uint4 ldsv[2560];    // 40 KB
  char* lk_ = (char*)ldsv;        // K tile: 64 slot-rows x 128 bf16 (256B rows, swz256, kv-permuted)
  char* lv_ = lk_ + 16384;        // V^T tile: 128 rows(d) x 64 bf16 (128B rows, swz128)
  char* lp_ = lk_ + 32768;        // P: 64 rows(q) x 64 bf16 (128B rows, swz128) - wave-private rows
  const int tid = threadIdx.x, lane = tid&63, w = tid>>6;
  const int l15 = lane&15, l4 = lane>>4;
  const int qb = blockIdx.x, b = blockIdx.y, h = blockIdx.z;
  const float invT = 0.088388347648318447f;   // 1/sqrt(128)
  const f32x4 zero4 = {0.f,0.f,0.f,0.f};

  bf16x8 qf[4];    // Q fragment: row = this wave's q (l15), k = d (contiguous 8)
  {
    const u16* qp = qh + (size_t)(b*1024 + qb*64 + w*16 + l15)*1024 + h*128 + l4*8;
    #pragma unroll
    for (int kk=0;kk<4;++kk)
      qf[kk] = __builtin_bit_cast(bf16x8, *reinterpret_cast<const uint4*>(qp + kk*32));
  }
  f32x4 oacc[8];
  #pragma unroll
  for (int i=0;i<8;++i) oacc[i] = zero4;
  float mr[4], lr[4];
  #pragma unroll
  for (int r=0;r<4;++r){ mr[r] = -3.0e38f; lr[r] = 0.f; }

  const int qglob = qb*64 + w*16 + l4*4;

  for (int kt=0; kt<16; ++kt){
    __syncthreads();            // prev iter done reading lk_/lv_
    // --- stage K (permuted+swizzled) and V^T (swizzled) via global_load_lds ---
    #pragma unroll
    for (int it=0; it<4; ++it){
      int slot = it*256 + tid;
      { int rs = slot>>4, cs = slot&15;
        int cg = cs ^ (rs&7);
        int kv = (rs&15)*4 + (rs>>4);
        gload16(kh + (size_t)(b*1024 + kt*64 + kv)*1024 + h*128 + cg*8,
                lk_ + (it*256 + w*64)*16); }
      { int r = slot>>3, cg = (slot&7) ^ (r&7);
        gload16(vt + (size_t)(b*1024 + h*128 + r)*1024 + kt*64 + cg*8,
                lv_ + (it*256 + w*64)*16); }
    }
    // --- issue old_score/mask float4 loads early (overlap staging) ---
    size_t rbase = ((size_t)(h*8 + b)*1024 + qglob)*1024 + kt*64 + l15*4;
    size_t mbase = ((size_t)b*1024 + qglob)*1024 + kt*64 + l15*4;
    float4 o4[4], m4[4];
    #pragma unroll
    for (int r=0;r<4;++r){
      o4[r] = *reinterpret_cast<const float4*>(oldsc + rbase + (size_t)r*1024);
      m4[r] = *reinterpret_cast<const float4*>(fmask + mbase + (size_t)r*1024);
    }
    __syncthreads();            // staging (and o4/m4) complete
    // --- S = Q K^T ---
    f32x4 fs[4];
    #pragma unroll
    for (int fj=0;fj<4;++fj){
      f32x4 s = zero4;
      #pragma unroll
      for (int kk=0;kk<4;++kk){
        bf16x8 kf = *reinterpret_cast<const bf16x8*>(lk_ + swz256(fj*16+l15, (kk*32+l4*8)*2));
        s = MFMA16(qf[kk], kf, s);
      }
      fs[fj] = s;
    }
    // --- raw out + mask + row-max (all float4 per row) ---
    float tm[4];
    #pragma unroll
    for (int r=0;r<4;++r){
      float4 rv;
      rv.x = fs[0][r] + o4[r].x; rv.y = fs[1][r] + o4[r].y;
      rv.z = fs[2][r] + o4[r].z; rv.w = fs[3][r] + o4[r].w;
      *reinterpret_cast<float4*>(raw + rbase + (size_t)r*1024) = rv;
      fs[0][r] = (rv.x - 1.0e8f*(1.0f - m4[r].x)) * invT;
      fs[1][r] = (rv.y - 1.0e8f*(1.0f - m4[r].y)) * invT;
      fs[2][r] = (rv.z - 1.0e8f*(1.0f - m4[r].z)) * invT;
      fs[3][r] = (rv.w - 1.0e8f*(1.0f - m4[r].w)) * invT;
      tm[r] = fmaxf(fmaxf(fs[0][r], fs[1][r]), fmaxf(fs[2][r], fs[3][r]));
    }
    #pragma unroll
    for (int o=1;o<16;o<<=1){
      #pragma unroll
      for (int r=0;r<4;++r) tm[r] = fmaxf(tm[r], __shfl_xor(tm[r], o));
    }
    #pragma unroll
    for (int r=0;r<4;++r){
      float mn  = fmaxf(mr[r], tm[r]);
      float esc = __expf(mr[r] - mn);
      mr[r] = mn;
      lr[r] *= esc;
      #pragma unroll
      for (int nf=0;nf<8;++nf) oacc[nf][r] *= esc;
      float px = __expf(fs[0][r] - mn), py = __expf(fs[1][r] - mn);
      float pz = __expf(fs[2][r] - mn), pw = __expf(fs[3][r] - mn);
      lr[r] += px + py + pz + pw;
      ushort4 o;
      o.x = f2bf(px); o.y = f2bf(py); o.z = f2bf(pz); o.w = f2bf(pw);
      int prow = w*16 + l4*4 + r;
      *reinterpret_cast<ushort4*>(lp_ + swz128(prow, l15*8)) = o;   // kv cols l15*4..+3
    }
    // --- PV: A = P (row q=l15, kv contiguous), B = V^T rows (col d, kv contiguous) ---
    #pragma unroll
    for (int kkv=0;kkv<2;++kkv){
      bf16x8 pf = *reinterpret_cast<const bf16x8*>(lp_ + swz128(w*16+l15, (kkv*32+l4*8)*2));
      #pragma unroll
      for (int nf=0;nf<8;++nf){
        bf16x8 vf = *reinterpret_cast<const bf16x8*>(lv_ + swz128(nf*16+l15, (kkv*32+l4*8)*2));
        oacc[nf] = MFMA16(pf, vf, oacc[nf]);
      }
    }
  }
  #pragma unroll
  for (int o=1;o<16;o<<=1){
    #pragma unroll
    for (int r=0;r<4;++r) lr[r] += __shfl_xor(lr[r], o);
  }
  #pragma unroll
  for (int nf=0;nf<8;++nf){
    int col = h*128 + nf*16 + l15;
    #pragma unroll
    for (int r=0;r<4;++r){
      size_t orow = (size_t)(b*1024 + qb*64 + w*16 + l4*4 + r);
      ao[orow*1024 + col] = f2bf(oacc[nf][r] * (1.0f/lr[r]));
    }
  }
}

// ---------------- LayerNorm (in-place, row=1024) ----------------
__global__ __launch_bounds__(256) void ln_k(float* __restrict__ io,
    const float* __restrict__ g, const float* __restrict__ bb)
{
  const int lane = threadIdx.x & 63, w = threadIdx.x >> 6;
  size_t row = (size_t)blockIdx.x*4 + w;
  float4* p = reinterpret_cast<float4*>(io + row*1024);
  float4 x[4];
  float s = 0.f, s2 = 0.f;
  #pragma unroll
  for (int i=0;i<4;++i){
    x[i] = p[lane + i*64];
    s  += x[i].x + x[i].y + x[i].z + x[i].w;
    s2 += x[i].x*x[i].x + x[i].y*x[i].y + x[i].z*x[i].z + x[i].w*x[i].w;
  }
  #pragma unroll
  for (int o=1;o<64;o<<=1){ s += __shfl_xor(s,o); s2 += __shfl_xor(s2,o); }
  float mean = s * 0.0009765625f;
  float var  = s2 * 0.0009765625f - mean*mean;
  float rstd = rsqrtf(var + 1e-5f);
  const float4* gp = reinterpret_cast<const float4*>(g);
  const float4* bp = reinterpret_cast<const float4*>(bb);
  #pragma unroll
  for (int i=0;i<4;++i){
    float4 gg = gp[lane+i*64], bv = bp[lane+i*64], y;
    y.x = (x[i].x-mean)*rstd*gg.x + bv.x;
    y.y = (x[i].y-mean)*rstd*gg.y + bv.y;
    y.z = (x[i].z-mean)*rstd*gg.z + bv.z;
    y.w = (x[i].w-mean)*rstd*gg.w + bv.w;
    p[lane+i*64] = y;
  }
}

extern "C" void kernel_launch(void* const* d_in, const int* in_sizes, int n_in,
                              void* d_out, int out_size, void* d_ws, size_t ws_size,
                              hipStream_t stream)
{
  const float* q    = (const float*)d_in[0];
  const float* k    = (const float*)d_in[1];
  const float* v    = (const float*)d_in[2];
  const float* olds = (const float*)d_in[3];
  const float* fm   = (const float*)d_in[4];
  const float* wq   = (const float*)d_in[5];
  const float* bq   = (const float*)d_in[6];
  const float* wk   = (const float*)d_in[7];
  const float* bk   = (const float*)d_in[8];
  const float* wv   = (const float*)d_in[9];
  const float* bv   = (const float*)d_in[10];
  const float* wfc  = (const float*)d_in[11];
  const float* bfc  = (const float*)d_in[12];
  const float* lng  = (const float*)d_in[13];
  const float* lnb  = (const float*)d_in[14];
  float* out = (float*)d_out;
  float* raw = out + 8388608;          // 8*1024*1024 fp32 "out", then 64M fp32 "raw"

  u16* ws  = (u16*)d_ws;
  u16* qbf = ws;                        // 8192x512
  u16* kbf = qbf + 4194304;             // 8192x512
  u16* vbf = kbf + 4194304;             // 8192x1024
  u16* wqb = vbf + 8388608;             // 1024x512
  u16* wkb = wqb + 524288;
  u16* wvb = wkb + 524288;              // 1024x1024
  u16* wfb = wvb + 1048576;
  u16* qhb = wfb + 1048576;             // 8192x1024
  u16* khb = qhb + 8388608;
  u16* vtb = khb + 8388608;             // [b][h*128+d][1024]
  u16* aob = vtb + 8388608;             // 8192x1024

  conv_f2b<<<4096,256,0,stream>>>(q,   qbf, 1048576);
  conv_f2b<<<4096,256,0,stream>>>(k,   kbf, 1048576);
  conv_f2b<<<8192,256,0,stream>>>(v,   vbf, 2097152);
  conv_f2b<<<512, 256,0,stream>>>(wq,  wqb, 131072);
  conv_f2b<<<512, 256,0,stream>>>(wk,  wkb, 131072);
  conv_f2b<<<1024,256,0,stream>>>(wv,  wvb, 262144);
  conv_f2b<<<1024,256,0,stream>>>(wfc, wfb, 262144);

  gemm_nt<0><<<dim3(64,8),256,0,stream>>>(qbf, wqb, bq, nullptr, qhb, nullptr, 8192,1024,512);
  gemm_nt<0><<<dim3(64,8),256,0,stream>>>(kbf, wkb, bk, nullptr, khb, nullptr, 8192,1024,512);
  gemm_nt<1><<<dim3(64,8),256,0,stream>>>(vbf, wvb, bv, nullptr, vtb, nullptr, 8192,1024,1024);

  attn_fused<<<dim3(16,8,8),256,0,stream>>>(qhb, khb, vtb, olds, fm, raw, aob);

  gemm_nt<2><<<dim3(64,8),256,0,stream>>>(aob, wfb, bfc, v, nullptr, out, 8192,1024,1024);
  ln_k<<<2048,256,0,stream>>>(out, lng, lnb);
}

// Round 3
// 313.164 us; speedup vs baseline: 1.0193x; 1.0095x over previous
//
#include <hip/hip_runtime.h>

typedef unsigned short u16;
typedef __bf16 bf16x8 __attribute__((ext_vector_type(8)));
typedef float f32x4 __attribute__((ext_vector_type(4)));

#define MFMA16(a,b,c) __builtin_amdgcn_mfma_f32_16x16x32_bf16(a,b,c,0,0,0)

static __device__ __forceinline__ u16 f2bf(float f){
  unsigned u = __builtin_bit_cast(unsigned, f);
  u += 0x7fffu + ((u>>16)&1u);
  return (u16)(u>>16);
}
static __device__ __forceinline__ int swz256(int r,int c){ return r*256 + (c ^ ((r&7)<<4)); }
static __device__ __forceinline__ int swz128(int r,int c){ return r*128 + (c ^ ((r&7)<<4)); }

// async global->LDS, 16B per lane; lds dest = wave-uniform base + lane*16
static __device__ __forceinline__ void gload16(const void* g, void* l){
  __builtin_amdgcn_global_load_lds(
      (const __attribute__((address_space(1))) unsigned int*)g,
      (__attribute__((address_space(3))) unsigned int*)l, 16, 0, 0);
}

// ---------------- fp32 -> bf16 convert ----------------
__global__ void conv_f2b(const float* __restrict__ in, u16* __restrict__ out, int n4){
  int i = blockIdx.x*256 + threadIdx.x;
  if (i >= n4) return;
  float4 f = reinterpret_cast<const float4*>(in)[i];
  ushort4 o; o.x=f2bf(f.x); o.y=f2bf(f.y); o.z=f2bf(f.z); o.w=f2bf(f.w);
  reinterpret_cast<ushort4*>(out)[i] = o;
}

// ---------------- bf16 NT GEMM: C[m][n] = sum_k A[m][k]*B[n][k] + bias[n] ----------------
template<int MODE>
__global__ __launch_bounds__(256) void gemm_nt(const u16* __restrict__ A, const u16* __restrict__ Bw,
    const float* __restrict__ bias, const float* __restrict__ resid,
    u16* __restrict__ Cb, float* __restrict__ Cf, int M, int N, int K)
{
  __shared__ uint4 ldsv[2048];               // 32 KB
  char* la = (char*)ldsv;
  char* lb = la + 16384;
  const int tid = threadIdx.x, lane = tid&63, w = tid>>6;
  const int l15 = lane&15, l4 = lane>>4;
  const int wm = w&1, wn = w>>1;
  const int mb = blockIdx.x, nb = blockIdx.y;
  const f32x4 zero4 = {0.f,0.f,0.f,0.f};
  f32x4 acc[4][4];
  #pragma unroll
  for (int i=0;i<4;++i)
    #pragma unroll
    for (int j=0;j<4;++j) acc[i][j] = zero4;

  for (int k0=0;k0<K;k0+=64){
    __syncthreads();
    #pragma unroll
    for (int it=0; it<4; ++it){
      int slot = it*256 + tid;
      int r = slot>>3, cg = (slot&7) ^ (r&7);
      gload16(A + (size_t)(mb*128+r)*K + k0 + cg*8, la + (it*256 + w*64)*16);
      gload16(Bw + (size_t)(nb*128+r)*K + k0 + cg*8, lb + (it*256 + w*64)*16);
    }
    __syncthreads();
    #pragma unroll
    for (int kk=0;kk<2;++kk){
      bf16x8 af[4], bfr[4];
      #pragma unroll
      for (int i=0;i<4;++i){
        af[i]  = *reinterpret_cast<const bf16x8*>(la + swz128(wm*64+i*16+l15, (kk*32+l4*8)*2));
        bfr[i] = *reinterpret_cast<const bf16x8*>(lb + swz128(wn*64+i*16+l15, (kk*32+l4*8)*2));
      }
      #pragma unroll
      for (int i=0;i<4;++i)
        #pragma unroll
        for (int j=0;j<4;++j)
          acc[i][j] = MFMA16(af[i], bfr[j], acc[i][j]);
    }
  }
  #pragma unroll
  for (int j=0;j<4;++j){
    int col = nb*128 + wn*64 + j*16 + l15;
    float bv = bias[col];
    #pragma unroll
    for (int i=0;i<4;++i){
      int row0 = mb*128 + wm*64 + i*16 + l4*4;
      if (MODE == 0){
        #pragma unroll
        for (int r=0;r<4;++r)
          Cb[(size_t)(row0+r)*N + col] = f2bf(acc[i][j][r] + bv);
      } else if (MODE == 1){
        int bb = row0 >> 10, kp = row0 & 1023;
        ushort4 o;
        o.x = f2bf(acc[i][j][0]+bv); o.y = f2bf(acc[i][j][1]+bv);
        o.z = f2bf(acc[i][j][2]+bv); o.w = f2bf(acc[i][j][3]+bv);
        *reinterpret_cast<ushort4*>(Cb + (size_t)(bb*1024+col)*1024 + kp) = o;
      } else {
        #pragma unroll
        for (int r=0;r<4;++r){
          size_t off = (size_t)(row0+r)*N + col;
          Cf[off] = acc[i][j][r] + bv + resid[off];
        }
      }
    }
  }
}

// ---------------- fused attention (double-buffered pipeline) ----------------
// grid (16, B=8, H=8), block 256 (4 waves, 16 q-rows each). KVB=64.
// K staged kv-PERMUTED so S-tile col for (fj,l15) = kv l15*4+fj -> float4 old/mask/raw.
// LDS: K/V double-buffered (stage t+1 issued before compute of t; single barrier/iter).
__global__ __launch_bounds__(256) void attn_fused(const u16* __restrict__ qh,
    const u16* __restrict__ kh, const u16* __restrict__ vt,
    const float* __restrict__ oldsc, const float* __restrict__ fmask,
    float* __restrict__ raw, u16* __restrict__ ao)
{
  __shared__ uint4 ldsv[4608];    // 72 KB
  char* lk0 = (char*)ldsv;        // K tile buf0: 64 x 128 bf16 (swz256, kv-permuted)
  char* lv0 = lk0 + 16384;        // V^T buf0: 128 x 64 bf16 (swz128)
  char* lk1 = lk0 + 32768;
  char* lv1 = lk0 + 49152;
  char* lp_ = lk0 + 65536;        // P: 64 x 64 bf16 (swz128), wave-private rows
  const int tid = threadIdx.x, lane = tid&63, w = tid>>6;
  const int l15 = lane&15, l4 = lane>>4;
  const int qb = blockIdx.x, b = blockIdx.y, h = blockIdx.z;
  const float invT = 0.088388347648318447f;   // 1/sqrt(128)
  const f32x4 zero4 = {0.f,0.f,0.f,0.f};

  const int qglob = qb*64 + w*16 + l4*4;
  const float* oldp = oldsc + ((size_t)(h*8+b)*1024 + qglob)*1024 + l15*4;
  const float* fmp  = fmask + ((size_t)b*1024 + qglob)*1024 + l15*4;
  float*       rawp = raw   + ((size_t)(h*8+b)*1024 + qglob)*1024 + l15*4;
  const u16* khB = kh + (size_t)b*1024*1024 + h*128;
  const u16* vtB = vt + ((size_t)b*1024 + h*128)*1024;

  bf16x8 qf[4];
  {
    const u16* qp = qh + (size_t)(b*1024 + qb*64 + w*16 + l15)*1024 + h*128 + l4*8;
    #pragma unroll
    for (int kk=0;kk<4;++kk)
      qf[kk] = __builtin_bit_cast(bf16x8, *reinterpret_cast<const uint4*>(qp + kk*32));
  }
  f32x4 oacc[8];
  #pragma unroll
  for (int i=0;i<8;++i) oacc[i] = zero4;
  float mr[4], lr[4];
  #pragma unroll
  for (int r=0;r<4;++r){ mr[r] = -3.0e38f; lr[r] = 0.f; }

  auto stage = [&](int kt, char* lkD, char* lvD){
    #pragma unroll
    for (int it=0; it<4; ++it){
      int slot = it*256 + tid;
      int rs = slot>>4, cs = slot&15;
      int cgk = cs ^ (rs&7);
      int kv = (rs&15)*4 + (rs>>4);
      gload16(khB + (size_t)(kt*64 + kv)*1024 + cgk*8, lkD + (it*256 + w*64)*16);
      int r8 = slot>>3, cgv = (slot&7) ^ (r8&7);
      gload16(vtB + (size_t)r8*1024 + kt*64 + cgv*8, lvD + (it*256 + w*64)*16);
    }
  };
  auto pref = [&](int kt, float4 (&o4)[4], float4 (&m4)[4]){
    #pragma unroll
    for (int r=0;r<4;++r){
      o4[r] = *reinterpret_cast<const float4*>(oldp + (size_t)r*1024 + kt*64);
      m4[r] = *reinterpret_cast<const float4*>(fmp  + (size_t)r*1024 + kt*64);
    }
  };
  auto body = [&](int kt, char* lkR, char* lvR, float4 (&o4)[4], float4 (&m4)[4]){
    f32x4 fs[4];
    #pragma unroll
    for (int fj=0;fj<4;++fj){
      f32x4 s = zero4;
      #pragma unroll
      for (int kk=0;kk<4;++kk){
        bf16x8 kf = *reinterpret_cast<const bf16x8*>(lkR + swz256(fj*16+l15, (kk*32+l4*8)*2));
        s = MFMA16(qf[kk], kf, s);
      }
      fs[fj] = s;
    }
    float tm[4];
    #pragma unroll
    for (int r=0;r<4;++r){
      float4 rv;
      rv.x = fs[0][r] + o4[r].x; rv.y = fs[1][r] + o4[r].y;
      rv.z = fs[2][r] + o4[r].z; rv.w = fs[3][r] + o4[r].w;
      *reinterpret_cast<float4*>(rawp + (size_t)r*1024 + kt*64) = rv;
      fs[0][r] = (rv.x - 1.0e8f*(1.0f - m4[r].x)) * invT;
      fs[1][r] = (rv.y - 1.0e8f*(1.0f - m4[r].y)) * invT;
      fs[2][r] = (rv.z - 1.0e8f*(1.0f - m4[r].z)) * invT;
      fs[3][r] = (rv.w - 1.0e8f*(1.0f - m4[r].w)) * invT;
      tm[r] = fmaxf(fmaxf(fs[0][r], fs[1][r]), fmaxf(fs[2][r], fs[3][r]));
    }
    #pragma unroll
    for (int o=1;o<16;o<<=1){
      #pragma unroll
      for (int r=0;r<4;++r) tm[r] = fmaxf(tm[r], __shfl_xor(tm[r], o));
    }
    #pragma unroll
    for (int r=0;r<4;++r){
      float mn  = fmaxf(mr[r], tm[r]);
      float esc = __expf(mr[r] - mn);
      mr[r] = mn;
      lr[r] *= esc;
      #pragma unroll
      for (int nf=0;nf<8;++nf) oacc[nf][r] *= esc;
      float px = __expf(fs[0][r] - mn), py = __expf(fs[1][r] - mn);
      float pz = __expf(fs[2][r] - mn), pw = __expf(fs[3][r] - mn);
      lr[r] += px + py + pz + pw;
      ushort4 o;
      o.x = f2bf(px); o.y = f2bf(py); o.z = f2bf(pz); o.w = f2bf(pw);
      int prow = w*16 + l4*4 + r;
      *reinterpret_cast<ushort4*>(lp_ + swz128(prow, l15*8)) = o;
    }
    #pragma unroll
    for (int kkv=0;kkv<2;++kkv){
      bf16x8 pf = *reinterpret_cast<const bf16x8*>(lp_ + swz128(w*16+l15, (kkv*32+l4*8)*2));
      #pragma unroll
      for (int nf=0;nf<8;++nf){
        bf16x8 vf = *reinterpret_cast<const bf16x8*>(lvR + swz128(nf*16+l15, (kkv*32+l4*8)*2));
        oacc[nf] = MFMA16(pf, vf, oacc[nf]);
      }
    }
    __syncthreads();   // implicit vmcnt(0)+lgkmcnt(0): next tile's stage+pref done,
                       // all waves done reading this tile's buffers
  };

  float4 oA[4], mA[4], oB[4], mB[4];
  stage(0, lk0, lv0);
  pref(0, oA, mA);
  __syncthreads();
  for (int kt=0; kt<16; kt+=2){
    stage(kt+1, lk1, lv1);
    pref(kt+1, oB, mB);
    body(kt, lk0, lv0, oA, mA);
    if (kt+2 < 16){ stage(kt+2, lk0, lv0); pref(kt+2, oA, mA); }
    body(kt+1, lk1, lv1, oB, mB);
  }

  #pragma unroll
  for (int o=1;o<16;o<<=1){
    #pragma unroll
    for (int r=0;r<4;++r) lr[r] += __shfl_xor(lr[r], o);
  }
  #pragma unroll
  for (int nf=0;nf<8;++nf){
    int col = h*128 + nf*16 + l15;
    #pragma unroll
    for (int r=0;r<4;++r){
      size_t orow = (size_t)(b*1024 + qb*64 + w*16 + l4*4 + r);
      ao[orow*1024 + col] = f2bf(oacc[nf][r] * (1.0f/lr[r]));
    }
  }
}

// ---------------- LayerNorm (in-place, row=1024) ----------------
__global__ __launch_bounds__(256) void ln_k(float* __restrict__ io,
    const float* __restrict__ g, const float* __restrict__ bb)
{
  const int lane = threadIdx.x & 63, w = threadIdx.x >> 6;
  size_t row = (size_t)blockIdx.x*4 + w;
  float4* p = reinterpret_cast<float4*>(io + row*1024);
  float4 x[4];
  float s = 0.f, s2 = 0.f;
  #pragma unroll
  for (int i=0;i<4;++i){
    x[i] = p[lane + i*64];
    s  += x[i].x + x[i].y + x[i].z + x[i].w;
    s2 += x[i].x*x[i].x + x[i].y*x[i].y + x[i].z*x[i].z + x[i].w*x[i].w;
  }
  #pragma unroll
  for (int o=1;o<64;o<<=1){ s += __shfl_xor(s,o); s2 += __shfl_xor(s2,o); }
  float mean = s * 0.0009765625f;
  float var  = s2 * 0.0009765625f - mean*mean;
  float rstd = rsqrtf(var + 1e-5f);
  const float4* gp = reinterpret_cast<const float4*>(g);
  const float4* bp = reinterpret_cast<const float4*>(bb);
  #pragma unroll
  for (int i=0;i<4;++i){
    float4 gg = gp[lane+i*64], bv = bp[lane+i*64], y;
    y.x = (x[i].x-mean)*rstd*gg.x + bv.x;
    y.y = (x[i].y-mean)*rstd*gg.y + bv.y;
    y.z = (x[i].z-mean)*rstd*gg.z + bv.z;
    y.w = (x[i].w-mean)*rstd*gg.w + bv.w;
    p[lane+i*64] = y;
  }
}

extern "C" void kernel_launch(void* const* d_in, const int* in_sizes, int n_in,
                              void* d_out, int out_size, void* d_ws, size_t ws_size,
                              hipStream_t stream)
{
  const float* q    = (const float*)d_in[0];
  const float* k    = (const float*)d_in[1];
  const float* v    = (const float*)d_in[2];
  const float* olds = (const float*)d_in[3];
  const float* fm   = (const float*)d_in[4];
  const float* wq   = (const float*)d_in[5];
  const float* bq   = (const float*)d_in[6];
  const float* wk   = (const float*)d_in[7];
  const float* bk   = (const float*)d_in[8];
  const float* wv   = (const float*)d_in[9];
  const float* bv   = (const float*)d_in[10];
  const float* wfc  = (const float*)d_in[11];
  const float* bfc  = (const float*)d_in[12];
  const float* lng  = (const float*)d_in[13];
  const float* lnb  = (const float*)d_in[14];
  float* out = (float*)d_out;
  float* raw = out + 8388608;          // 8*1024*1024 fp32 "out", then 64M fp32 "raw"

  u16* ws  = (u16*)d_ws;
  u16* qbf = ws;                        // 8192x512
  u16* kbf = qbf + 4194304;             // 8192x512
  u16* vbf = kbf + 4194304;             // 8192x1024
  u16* wqb = vbf + 8388608;             // 1024x512
  u16* wkb = wqb + 524288;
  u16* wvb = wkb + 524288;              // 1024x1024
  u16* wfb = wvb + 1048576;
  u16* qhb = wfb + 1048576;             // 8192x1024
  u16* khb = qhb + 8388608;
  u16* vtb = khb + 8388608;             // [b][h*128+d][1024]
  u16* aob = vtb + 8388608;             // 8192x1024

  conv_f2b<<<4096,256,0,stream>>>(q,   qbf, 1048576);
  conv_f2b<<<4096,256,0,stream>>>(k,   kbf, 1048576);
  conv_f2b<<<8192,256,0,stream>>>(v,   vbf, 2097152);
  conv_f2b<<<512, 256,0,stream>>>(wq,  wqb, 131072);
  conv_f2b<<<512, 256,0,stream>>>(wk,  wkb, 131072);
  conv_f2b<<<1024,256,0,stream>>>(wv,  wvb, 262144);
  conv_f2b<<<1024,256,0,stream>>>(wfc, wfb, 262144);

  gemm_nt<0><<<dim3(64,8),256,0,stream>>>(qbf, wqb, bq, nullptr, qhb, nullptr, 8192,1024,512);
  gemm_nt<0><<<dim3(64,8),256,0,stream>>>(kbf, wkb, bk, nullptr, khb, nullptr, 8192,1024,512);
  gemm_nt<1><<<dim3(64,8),256,0,stream>>>(vbf, wvb, bv, nullptr, vtb, nullptr, 8192,1024,1024);

  attn_fused<<<dim3(16,8,8),256,0,stream>>>(qhb, khb, vtb, olds, fm, raw, aob);

  gemm_nt<2><<<dim3(64,8),256,0,stream>>>(aob, wfb, bfc, v, nullptr, out, 8192,1024,1024);
  ln_k<<<2048,256,0,stream>>>(out, lng, lnb);
}